// Round 6
// baseline (142.954 us; speedup 1.0000x reference)
//
#include <hip/hip_runtime.h>
#include <hip/hip_bf16.h>
#include <math.h>

#define NQ 7
#define NL 6
#define BATCH 8192
#define NPCA 32
#define NCLS 3129
#define NGATE 42

#define NBQ 2048            // quantum blocks (4 samples each)
#define NBC 512             // chead blocks (16 rows each)
#define NBX 49              // transpose x-tiles = ceil(3129/64)
#define NBT (3 * NBX)       // transpose blocks

typedef __attribute__((ext_vector_type(8))) short short8;
typedef __attribute__((ext_vector_type(4))) float f32x4;

__device__ __forceinline__ void gload_lds16(const void* g, void* l) {
    __builtin_amdgcn_global_load_lds(
        (const __attribute__((address_space(1))) void*)g,
        (__attribute__((address_space(3))) void*)l, 16, 0, 0);
}

// ---------------------------------------------------------------------------
// Fused prep kernel: blockIdx.x selects role.
//   [0, NBQ)            quantum circuit (one wave/sample, 4 samples/block)
//   [NBQ, NBQ+NBC)      classical head layers 1+2
//   [NBQ+NBC, +NBT)     weight transpose+cast
// ---------------------------------------------------------------------------
__global__ __launch_bounds__(256) void prep_kernel(
    const float* __restrict__ x,        // B x 32
    const float* __restrict__ fscale,   // 32
    const float* __restrict__ qw,       // 6 x 7 x 2
    const float* __restrict__ qh_w1,    // 7 x 64
    const float* __restrict__ qh_b1,    // 64
    const float* __restrict__ cw1, const float* __restrict__ cb1,
    const float* __restrict__ cw2, const float* __restrict__ cb2,
    const float* __restrict__ qw2, const float* __restrict__ cw3,
    float* __restrict__ qf_out,             // B x 7 fp32 (d_out)
    __hip_bfloat16* __restrict__ hq_out,    // B x 64
    __hip_bfloat16* __restrict__ h2_out,    // B x 128
    __hip_bfloat16* __restrict__ qw2t,      // 3200 x 64
    __hip_bfloat16* __restrict__ cw3t)      // 3200 x 128
{
    __shared__ alignas(16) unsigned char smem[18752];
    const int bid = blockIdx.x;
    const int tid = threadIdx.x;

    if (bid < NBQ) {
        // ================= quantum role =================
        float* pzc = (float*)smem;
        float* pzs = pzc + NGATE;
        float* w0s = pzs + NGATE;
        if (tid < NGATE) {
            float t = qw[tid * 2 + 1] * 0.5f;
            float s, c;
            sincosf(t, &s, &c);
            pzs[tid] = s; pzc[tid] = c;
            w0s[tid] = qw[tid * 2 + 0];
        }
        __syncthreads();

        const int lane = tid & 63;
        const int wave = tid >> 6;
        const int sample = bid * 4 + wave;

        float myfeat = 0.f;
        if (lane < NPCA) myfeat = atanf(x[sample * NPCA + lane] * fscale[lane]);

        // hoisted per-gate trig: lane g owns gate g's sin/cos (assignment under
        // divergence is fine; the shuffles that READ sv/cv are in uniform flow)
        float sv = 0.f, cv = 1.f;
        if (lane < NGATE) {
            float th = (((lane < NPCA) ? myfeat : 0.f) + w0s[lane]) * 0.5f;
            sv = __sinf(th); cv = __cosf(th);   // |th| < 1 rad: HW trig safe
        }

        // CNOT-ring net permutation (verified GF(2) algebra):
        //   src_lane(slot0) = lane ^ (lane>>1); src_lane(slot1) = that ^ 48;
        //   src_slot = dst-lane parity (slot0), inverted (slot1).
        const int t0 = (lane ^ (lane >> 1)) & 63;
        const int t1 = t0 ^ 48;
        const bool odd = (lane & 1) != 0;

        float s0r = (lane == 0) ? 1.f : 0.f, s0i = 0.f, s1r = 0.f, s1i = 0.f;

        for (int layer = 0; layer < NL; ++layer) {
            #pragma unroll
            for (int q = 0; q < NQ; ++q) {
                const int g = layer * NQ + q;
                const int b = NQ - 1 - q;
                float s = __shfl(sv, g), c = __shfl(cv, g);
                if (b == 0) {
                    float n0r = c * s0r - s * s1r, n0i = c * s0i - s * s1i;
                    float n1r = s * s0r + c * s1r, n1i = s * s0i + c * s1i;
                    s0r = n0r; s0i = n0i; s1r = n1r; s1i = n1i;
                } else {
                    int m = 1 << (b - 1);
                    float p0r = __shfl_xor(s0r, m), p0i = __shfl_xor(s0i, m);
                    float p1r = __shfl_xor(s1r, m), p1i = __shfl_xor(s1i, m);
                    if (((lane >> (b - 1)) & 1) == 0) {
                        s0r = c * s0r - s * p0r; s0i = c * s0i - s * p0i;
                        s1r = c * s1r - s * p1r; s1i = c * s1i - s * p1i;
                    } else {
                        s0r = s * p0r + c * s0r; s0i = s * p0i + c * s0i;
                        s1r = s * p1r + c * s1r; s1i = s * p1i + c * s1i;
                    }
                }
                float pc = pzc[g], ps = pzs[g];
                if (b == 0) {
                    float u0 = pc * s0r + ps * s0i; s0i = pc * s0i - ps * s0r; s0r = u0;
                    float u1 = pc * s1r - ps * s1i; s1i = pc * s1i + ps * s1r; s1r = u1;
                } else {
                    float e = (((lane >> (b - 1)) & 1) == 0) ? ps : -ps;
                    float u0 = pc * s0r + e * s0i; s0i = pc * s0i - e * s0r; s0r = u0;
                    float u1 = pc * s1r + e * s1i; s1i = pc * s1i - e * s1r; s1r = u1;
                }
            }
            // CNOT ring permutation. CONVERGENCE: all 8 bpermutes execute
            // unconditionally in uniform flow (a shuffle inside a divergent
            // ternary arm pulls 0 from exec-masked source lanes -> R5 bug).
            float a0r = __shfl(s0r, t0), a0i = __shfl(s0i, t0);
            float a1r = __shfl(s1r, t0), a1i = __shfl(s1i, t0);
            float b0r = __shfl(s0r, t1), b0i = __shfl(s0i, t1);
            float b1r = __shfl(s1r, t1), b1i = __shfl(s1i, t1);
            s0r = odd ? a1r : a0r;  s0i = odd ? a1i : a0i;
            s1r = odd ? b0r : b1r;  s1i = odd ? b0i : b1i;
        }

        float p0 = s0r * s0r + s0i * s0i;
        float p1 = s1r * s1r + s1i * s1i;
        float psum = p0 + p1;
        float qf[7];
        #pragma unroll
        for (int k = 0; k < 6; ++k)
            qf[k] = (((lane >> (5 - k)) & 1) ? -psum : psum);
        qf[6] = p0 - p1;
        #pragma unroll
        for (int off = 32; off >= 1; off >>= 1) {
            #pragma unroll
            for (int k = 0; k < 7; ++k) qf[k] += __shfl_xor(qf[k], off);
        }

        float acc = qh_b1[lane];
        #pragma unroll
        for (int k = 0; k < 7; ++k) acc += qf[k] * qh_w1[k * 64 + lane];
        hq_out[sample * 64 + lane] = __float2bfloat16(fmaxf(acc, 0.f));
        if (lane < 7) qf_out[sample * 7 + lane] = qf[lane];

    } else if (bid < NBQ + NBC) {
        // ================= chead role =================
        float (*xs)[33]   = (float(*)[33])smem;            // 2112 B
        float (*h1s)[260] = (float(*)[260])(smem + 2112);  // 16640 B
        const int row0 = (bid - NBQ) * 16;

        for (int i = tid; i < 16 * 32; i += 256) {
            int r = i >> 5, k = i & 31;
            xs[r][k] = x[(row0 + r) * 32 + k];
        }
        __syncthreads();

        {
            float w1c[32];
            #pragma unroll
            for (int k = 0; k < 32; ++k) w1c[k] = cw1[k * 256 + tid];
            float bb = cb1[tid];
            #pragma unroll
            for (int r = 0; r < 16; ++r) {
                float a = bb;
                #pragma unroll
                for (int k = 0; k < 32; ++k) a += xs[r][k] * w1c[k];
                h1s[r][tid] = fmaxf(a, 0.f);
            }
        }
        __syncthreads();

        {
            const int c0 = (tid & 31) * 4;
            const int r0 = (tid >> 5) * 2;
            float4 bv = *(const float4*)&cb2[c0];
            float a0[4] = {bv.x, bv.y, bv.z, bv.w};
            float a1[4] = {bv.x, bv.y, bv.z, bv.w};
            for (int k = 0; k < 256; k += 4) {
                float4 h0 = *(const float4*)&h1s[r0][k];
                float4 h1 = *(const float4*)&h1s[r0 + 1][k];
                #pragma unroll
                for (int j = 0; j < 4; ++j) {
                    float4 w = *(const float4*)&cw2[(size_t)(k + j) * 128 + c0];
                    float hv0 = (j == 0) ? h0.x : (j == 1) ? h0.y : (j == 2) ? h0.z : h0.w;
                    float hv1 = (j == 0) ? h1.x : (j == 1) ? h1.y : (j == 2) ? h1.z : h1.w;
                    a0[0] += hv0 * w.x; a0[1] += hv0 * w.y; a0[2] += hv0 * w.z; a0[3] += hv0 * w.w;
                    a1[0] += hv1 * w.x; a1[1] += hv1 * w.y; a1[2] += hv1 * w.z; a1[3] += hv1 * w.w;
                }
            }
            #pragma unroll
            for (int rr = 0; rr < 2; ++rr) {
                float* a = rr ? a1 : a0;
                __hip_bfloat162 q0, q1;
                q0.x = __float2bfloat16(fmaxf(a[0], 0.f));
                q0.y = __float2bfloat16(fmaxf(a[1], 0.f));
                q1.x = __float2bfloat16(fmaxf(a[2], 0.f));
                q1.y = __float2bfloat16(fmaxf(a[3], 0.f));
                size_t base = (size_t)(row0 + r0 + rr) * 128 + c0;
                *(__hip_bfloat162*)&h2_out[base]     = q0;
                *(__hip_bfloat162*)&h2_out[base + 2] = q1;
            }
        }

    } else {
        // ================= transpose role =================
        float (*tile)[65] = (float(*)[65])smem;            // 16640 B
        const int t = bid - (NBQ + NBC);
        const int y = t / NBX;
        const int n0 = (t % NBX) * 64;
        const float* W; __hip_bfloat16* Wt; int K, k0;
        if (y == 0) { W = qw2; Wt = qw2t; K = 64;  k0 = 0; }
        else        { W = cw3; Wt = cw3t; K = 128; k0 = (y - 1) * 64; }

        #pragma unroll
        for (int i = 0; i < 16; ++i) {
            int id = tid + i * 256;
            int kr = id >> 6, nc = id & 63;
            int n = n0 + nc;
            tile[kr][nc] = (n < NCLS) ? W[(size_t)(k0 + kr) * NCLS + n] : 0.f;
        }
        __syncthreads();
        #pragma unroll
        for (int i = 0; i < 16; ++i) {
            int id = tid + i * 256;
            int nr = id >> 6, kc = id & 63;
            int n = n0 + nr;
            if (n < NCLS) Wt[(size_t)n * K + k0 + kc] = __float2bfloat16(tile[kc][nr]);
        }
    }
}

// ---------------------------------------------------------------------------
// Dual MFMA GEMM (z=0: K=64 q-head; z=1: K=128 c-head). 128x128 tile, 4 waves.
// global_load_lds w=16 staging with XOR-swizzled source chunks; LDS-staged
// epilogue with full-wave contiguous NON-TEMPORAL dword stores.
// ---------------------------------------------------------------------------
__global__ __launch_bounds__(256) void gemm_mfma_dual(
    const __hip_bfloat16* __restrict__ A0, const __hip_bfloat16* __restrict__ B0,
    const float* __restrict__ bias0, float* __restrict__ C0,
    const __hip_bfloat16* __restrict__ A1, const __hip_bfloat16* __restrict__ B1,
    const float* __restrict__ bias1, float* __restrict__ C1, int N)
{
    __shared__ alignas(16) unsigned char shraw[32768];
    __hip_bfloat16* Alds = (__hip_bfloat16*)shraw;           // 128 x 64 (16 KB)
    __hip_bfloat16* Blds = Alds + 128 * 64;                  // 128 x 64 (16 KB)
    float* scr = (float*)shraw;                              // 64 x 128 fp32 (32 KB)

    const int z = blockIdx.z;
    const __hip_bfloat16* A  = z ? A1 : A0;
    const __hip_bfloat16* Bt = z ? B1 : B0;
    const float* bias        = z ? bias1 : bias0;
    float* C                 = z ? C1 : C0;
    const int K              = z ? 128 : 64;

    const int tid  = threadIdx.x;
    const int lane = tid & 63;
    const int wave = tid >> 6;
    const int wr = wave >> 1, wc = wave & 1;
    const int row0 = blockIdx.y * 128;
    const int col0 = blockIdx.x * 128;

    f32x4 acc[4][4] = {};

    for (int kb = 0; kb < K; kb += 64) {
        #pragma unroll
        for (int i = 0; i < 4; ++i) {
            int id = tid + i * 256;
            int r = id >> 3;
            int c = id & 7;
            int cs = c ^ (r & 7);
            gload_lds16(&A[(size_t)(row0 + r) * K + kb + cs * 8], &Alds[id * 8]);
        }
        #pragma unroll
        for (int i = 0; i < 4; ++i) {
            int id = tid + i * 256;
            int r = id >> 3;
            int c = id & 7;
            int cs = c ^ (r & 7);
            int n = col0 + r;
            if (n >= N) n = N - 1;            // clamp: garbage cols never stored
            gload_lds16(&Bt[(size_t)n * K + kb + cs * 8], &Blds[id * 8]);
        }
        __syncthreads();

        const int frow = lane & 15;
        const int chi  = lane >> 4;
        #pragma unroll
        for (int kk = 0; kk < 2; ++kk) {
            short8 af[4], bf[4];
            #pragma unroll
            for (int m = 0; m < 4; ++m) {
                int r = wr * 64 + m * 16 + frow;
                int cs = (kk * 4 + chi) ^ (r & 7);
                af[m] = *(const short8*)&Alds[r * 64 + cs * 8];
            }
            #pragma unroll
            for (int n = 0; n < 4; ++n) {
                int r = wc * 64 + n * 16 + frow;
                int cs = (kk * 4 + chi) ^ (r & 7);
                bf[n] = *(const short8*)&Blds[r * 64 + cs * 8];
            }
            #pragma unroll
            for (int m = 0; m < 4; ++m)
                #pragma unroll
                for (int n = 0; n < 4; ++n)
                    acc[m][n] = __builtin_amdgcn_mfma_f32_16x16x32_bf16(
                        af[m], bf[n], acc[m][n], 0, 0, 0);
        }
        __syncthreads();
    }

    // ---- epilogue: 2 passes of 64 rows x 128 cols through LDS ----
    const int g = lane >> 4;
    const int fcol = lane & 15;
    const int ccr = tid & 127;
    const int bc  = col0 + ccr;
    const float bv = (bc < N) ? bias[bc] : 0.f;

    #pragma unroll
    for (int p = 0; p < 2; ++p) {
        if (p) __syncthreads();
        #pragma unroll
        for (int mm = 0; mm < 2; ++mm) {
            #pragma unroll
            for (int n = 0; n < 4; ++n) {
                int rl = wr * 32 + mm * 16 + g * 4;
                int cc = wc * 64 + n * 16 + fcol;
                int ccs = cc ^ (((rl >> 2) & 1) << 4);
                #pragma unroll
                for (int r = 0; r < 4; ++r)
                    scr[(rl + r) * 128 + ccs] = acc[2 * p + mm][n][r];
            }
        }
        __syncthreads();
        if (bc < N) {
            #pragma unroll
            for (int i = 0; i < 32; ++i) {
                int id = i * 256 + tid;
                int rl = id >> 7;
                int ccs = ccr ^ (((rl >> 2) & 1) << 4);
                int grow = row0 + p * 32 + ((rl >> 5) << 6) + (rl & 31);
                __builtin_nontemporal_store(scr[rl * 128 + ccs] + bv,
                                            &C[(size_t)grow * N + bc]);
            }
        }
    }
}

extern "C" void kernel_launch(void* const* d_in, const int* in_sizes, int n_in,
                              void* d_out, int out_size, void* d_ws, size_t ws_size,
                              hipStream_t stream)
{
    const float* x   = (const float*)d_in[0];
    const float* fs  = (const float*)d_in[1];
    const float* qw  = (const float*)d_in[2];
    const float* qw1 = (const float*)d_in[3];
    const float* qb1 = (const float*)d_in[4];
    const float* qw2 = (const float*)d_in[5];
    const float* qb2 = (const float*)d_in[6];
    const float* cw1 = (const float*)d_in[7];
    const float* cb1 = (const float*)d_in[8];
    const float* cw2 = (const float*)d_in[9];
    const float* cb2 = (const float*)d_in[10];
    const float* cw3 = (const float*)d_in[11];
    const float* cb3 = (const float*)d_in[12];

    float* q_logits = (float*)d_out;
    float* c_logits = q_logits + (size_t)BATCH * NCLS;
    float* qf_out   = c_logits + (size_t)BATCH * NCLS;

    const int NPAD = 3200;
    __hip_bfloat16* hq   = (__hip_bfloat16*)d_ws;              // 8192 x 64
    __hip_bfloat16* h2   = hq + (size_t)BATCH * 64;            // 8192 x 128
    __hip_bfloat16* qw2t = h2 + (size_t)BATCH * 128;           // 3200 x 64
    __hip_bfloat16* cw3t = qw2t + (size_t)NPAD * 64;           // 3200 x 128

    prep_kernel<<<NBQ + NBC + NBT, 256, 0, stream>>>(
        x, fs, qw, qw1, qb1, cw1, cb1, cw2, cb2, qw2, cw3,
        qf_out, hq, h2, qw2t, cw3t);

    dim3 grid((NCLS + 127) / 128, BATCH / 128, 2);
    gemm_mfma_dual<<<grid, 256, 0, stream>>>(hq, qw2t, qb2, q_logits,
                                             h2, cw3t, cb3, c_logits, NCLS);
}

// Round 7
// 103.313 us; speedup vs baseline: 1.3837x; 1.3837x over previous
//
#include <hip/hip_runtime.h>
#include <hip/hip_bf16.h>
#include <math.h>

#define NQ 7
#define NL 6
#define BATCH 8192
#define NPCA 32
#define NCLS 3129
#define NGATE 42

#define NBQ 2048            // quantum blocks (4 samples each)
#define NBC 512             // chead blocks (16 rows each)
#define NBX 49              // transpose x-tiles = ceil(3129/64)
#define NBT (3 * NBX)       // transpose blocks

typedef __attribute__((ext_vector_type(8))) short short8;
typedef __attribute__((ext_vector_type(4))) float f32x4;

__device__ __forceinline__ void gload_lds16(const void* g, void* l) {
    __builtin_amdgcn_global_load_lds(
        (const __attribute__((address_space(1))) void*)g,
        (__attribute__((address_space(3))) void*)l, 16, 0, 0);
}

// ---------------------------------------------------------------------------
// Fused prep kernel: blockIdx.x selects role. Quantum math is the PROVEN R4
// version: per-gate __sinf/__cosf (trans pipe, serial-chain-friendly) and
// sequential CNOT ring via shfl_xor with CONSTANT masks (DPP, not bpermute).
// ---------------------------------------------------------------------------
__global__ __launch_bounds__(256) void prep_kernel(
    const float* __restrict__ x,        // B x 32
    const float* __restrict__ fscale,   // 32
    const float* __restrict__ qw,       // 6 x 7 x 2
    const float* __restrict__ qh_w1,    // 7 x 64
    const float* __restrict__ qh_b1,    // 64
    const float* __restrict__ cw1, const float* __restrict__ cb1,
    const float* __restrict__ cw2, const float* __restrict__ cb2,
    const float* __restrict__ qw2, const float* __restrict__ cw3,
    float* __restrict__ qf_out,             // B x 7 fp32 (d_out)
    __hip_bfloat16* __restrict__ hq_out,    // B x 64
    __hip_bfloat16* __restrict__ h2_out,    // B x 128
    __hip_bfloat16* __restrict__ qw2t,      // 3200 x 64
    __hip_bfloat16* __restrict__ cw3t)      // 3200 x 128
{
    __shared__ alignas(16) unsigned char smem[18752];
    const int bid = blockIdx.x;
    const int tid = threadIdx.x;

    if (bid < NBQ) {
        // ================= quantum role (R4-proven math) =================
        float* pzc = (float*)smem;
        float* pzs = pzc + NGATE;
        float* w0s = pzs + NGATE;
        if (tid < NGATE) {
            float t = qw[tid * 2 + 1] * 0.5f;
            float s, c;
            sincosf(t, &s, &c);
            pzs[tid] = s; pzc[tid] = c;
            w0s[tid] = qw[tid * 2 + 0];
        }
        __syncthreads();

        const int lane = tid & 63;
        const int wave = tid >> 6;
        const int sample = bid * 4 + wave;

        float myfeat = 0.f;
        if (lane < NPCA) myfeat = atanf(x[sample * NPCA + lane] * fscale[lane]);

        float s0r = (lane == 0) ? 1.f : 0.f, s0i = 0.f, s1r = 0.f, s1i = 0.f;

        for (int layer = 0; layer < NL; ++layer) {
            for (int q = 0; q < NQ; ++q) {
                const int g = layer * NQ + q;
                const int b = NQ - 1 - q;
                float fv = (g < NPCA) ? __shfl(myfeat, g) : 0.f;
                float th = (fv + w0s[g]) * 0.5f;
                float s = __sinf(th), c = __cosf(th);   // |th| < 1 rad: HW trig safe
                if (b == 0) {
                    float n0r = c * s0r - s * s1r, n0i = c * s0i - s * s1i;
                    float n1r = s * s0r + c * s1r, n1i = s * s0i + c * s1i;
                    s0r = n0r; s0i = n0i; s1r = n1r; s1i = n1i;
                } else {
                    int m = 1 << (b - 1);
                    float p0r = __shfl_xor(s0r, m), p0i = __shfl_xor(s0i, m);
                    float p1r = __shfl_xor(s1r, m), p1i = __shfl_xor(s1i, m);
                    if (((lane >> (b - 1)) & 1) == 0) {
                        s0r = c * s0r - s * p0r; s0i = c * s0i - s * p0i;
                        s1r = c * s1r - s * p1r; s1i = c * s1i - s * p1i;
                    } else {
                        s0r = s * p0r + c * s0r; s0i = s * p0i + c * s0i;
                        s1r = s * p1r + c * s1r; s1i = s * p1i + c * s1i;
                    }
                }
                float pc = pzc[g], ps = pzs[g];
                if (b == 0) {
                    float u0 = pc * s0r + ps * s0i; s0i = pc * s0i - ps * s0r; s0r = u0;
                    float u1 = pc * s1r - ps * s1i; s1i = pc * s1i + ps * s1r; s1r = u1;
                } else {
                    float e = (((lane >> (b - 1)) & 1) == 0) ? ps : -ps;
                    float u0 = pc * s0r + e * s0i; s0i = pc * s0i - e * s0r; s0r = u0;
                    float u1 = pc * s1r + e * s1i; s1i = pc * s1i - e * s1r; s1r = u1;
                }
            }
            // sequential CNOT ring: constant-mask shfl_xor -> DPP/swizzle
            #pragma unroll
            for (int cq = 0; cq < NQ; ++cq) {
                if (cq == NQ - 1) {
                    float r = __shfl_xor(s1r, 32), im = __shfl_xor(s1i, 32);
                    s1r = r; s1i = im;
                } else if (cq == NQ - 2) {
                    if (lane & 1) {
                        float tr = s0r; s0r = s1r; s1r = tr;
                        float ti = s0i; s0i = s1i; s1i = ti;
                    }
                } else {
                    const int bc = NQ - 1 - cq;
                    const int bt = bc - 1;
                    int m = 1 << (bt - 1);
                    float p0r = __shfl_xor(s0r, m), p0i = __shfl_xor(s0i, m);
                    float p1r = __shfl_xor(s1r, m), p1i = __shfl_xor(s1i, m);
                    if ((lane >> (bc - 1)) & 1) {
                        s0r = p0r; s0i = p0i; s1r = p1r; s1i = p1i;
                    }
                }
            }
        }

        float p0 = s0r * s0r + s0i * s0i;
        float p1 = s1r * s1r + s1i * s1i;
        float psum = p0 + p1;
        float qf[7];
        #pragma unroll
        for (int k = 0; k < 6; ++k)
            qf[k] = (((lane >> (5 - k)) & 1) ? -psum : psum);
        qf[6] = p0 - p1;
        #pragma unroll
        for (int off = 32; off >= 1; off >>= 1) {
            #pragma unroll
            for (int k = 0; k < 7; ++k) qf[k] += __shfl_xor(qf[k], off);
        }

        float acc = qh_b1[lane];
        #pragma unroll
        for (int k = 0; k < 7; ++k) acc += qf[k] * qh_w1[k * 64 + lane];
        hq_out[sample * 64 + lane] = __float2bfloat16(fmaxf(acc, 0.f));
        if (lane < 7) qf_out[sample * 7 + lane] = qf[lane];

    } else if (bid < NBQ + NBC) {
        // ================= chead role =================
        float (*xs)[33]   = (float(*)[33])smem;            // 2112 B
        float (*h1s)[260] = (float(*)[260])(smem + 2112);  // 16640 B
        const int row0 = (bid - NBQ) * 16;

        for (int i = tid; i < 16 * 32; i += 256) {
            int r = i >> 5, k = i & 31;
            xs[r][k] = x[(row0 + r) * 32 + k];
        }
        __syncthreads();

        {
            float w1c[32];
            #pragma unroll
            for (int k = 0; k < 32; ++k) w1c[k] = cw1[k * 256 + tid];
            float bb = cb1[tid];
            #pragma unroll
            for (int r = 0; r < 16; ++r) {
                float a = bb;
                #pragma unroll
                for (int k = 0; k < 32; ++k) a += xs[r][k] * w1c[k];
                h1s[r][tid] = fmaxf(a, 0.f);
            }
        }
        __syncthreads();

        {
            const int c0 = (tid & 31) * 4;
            const int r0 = (tid >> 5) * 2;
            float4 bv = *(const float4*)&cb2[c0];
            float a0[4] = {bv.x, bv.y, bv.z, bv.w};
            float a1[4] = {bv.x, bv.y, bv.z, bv.w};
            for (int k = 0; k < 256; k += 4) {
                float4 h0 = *(const float4*)&h1s[r0][k];
                float4 h1 = *(const float4*)&h1s[r0 + 1][k];
                #pragma unroll
                for (int j = 0; j < 4; ++j) {
                    float4 w = *(const float4*)&cw2[(size_t)(k + j) * 128 + c0];
                    float hv0 = (j == 0) ? h0.x : (j == 1) ? h0.y : (j == 2) ? h0.z : h0.w;
                    float hv1 = (j == 0) ? h1.x : (j == 1) ? h1.y : (j == 2) ? h1.z : h1.w;
                    a0[0] += hv0 * w.x; a0[1] += hv0 * w.y; a0[2] += hv0 * w.z; a0[3] += hv0 * w.w;
                    a1[0] += hv1 * w.x; a1[1] += hv1 * w.y; a1[2] += hv1 * w.z; a1[3] += hv1 * w.w;
                }
            }
            #pragma unroll
            for (int rr = 0; rr < 2; ++rr) {
                float* a = rr ? a1 : a0;
                __hip_bfloat162 q0, q1;
                q0.x = __float2bfloat16(fmaxf(a[0], 0.f));
                q0.y = __float2bfloat16(fmaxf(a[1], 0.f));
                q1.x = __float2bfloat16(fmaxf(a[2], 0.f));
                q1.y = __float2bfloat16(fmaxf(a[3], 0.f));
                size_t base = (size_t)(row0 + r0 + rr) * 128 + c0;
                *(__hip_bfloat162*)&h2_out[base]     = q0;
                *(__hip_bfloat162*)&h2_out[base + 2] = q1;
            }
        }

    } else {
        // ================= transpose role =================
        float (*tile)[65] = (float(*)[65])smem;            // 16640 B
        const int t = bid - (NBQ + NBC);
        const int y = t / NBX;
        const int n0 = (t % NBX) * 64;
        const float* W; __hip_bfloat16* Wt; int K, k0;
        if (y == 0) { W = qw2; Wt = qw2t; K = 64;  k0 = 0; }
        else        { W = cw3; Wt = cw3t; K = 128; k0 = (y - 1) * 64; }

        #pragma unroll
        for (int i = 0; i < 16; ++i) {
            int id = tid + i * 256;
            int kr = id >> 6, nc = id & 63;
            int n = n0 + nc;
            tile[kr][nc] = (n < NCLS) ? W[(size_t)(k0 + kr) * NCLS + n] : 0.f;
        }
        __syncthreads();
        #pragma unroll
        for (int i = 0; i < 16; ++i) {
            int id = tid + i * 256;
            int nr = id >> 6, kc = id & 63;
            int n = n0 + nr;
            if (n < NCLS) Wt[(size_t)n * K + k0 + kc] = __float2bfloat16(tile[kc][nr]);
        }
    }
}

// ---------------------------------------------------------------------------
// Dual MFMA GEMM (z=0: K=64 q-head; z=1: K=128 c-head). 128x128 tile, 4 waves.
// global_load_lds w=16 staging with XOR-swizzled source chunks; LDS-staged
// epilogue with full-wave contiguous PLAIN dword stores (NT store regressed).
// ---------------------------------------------------------------------------
__global__ __launch_bounds__(256) void gemm_mfma_dual(
    const __hip_bfloat16* __restrict__ A0, const __hip_bfloat16* __restrict__ B0,
    const float* __restrict__ bias0, float* __restrict__ C0,
    const __hip_bfloat16* __restrict__ A1, const __hip_bfloat16* __restrict__ B1,
    const float* __restrict__ bias1, float* __restrict__ C1, int N)
{
    __shared__ alignas(16) unsigned char shraw[32768];
    __hip_bfloat16* Alds = (__hip_bfloat16*)shraw;           // 128 x 64 (16 KB)
    __hip_bfloat16* Blds = Alds + 128 * 64;                  // 128 x 64 (16 KB)
    float* scr = (float*)shraw;                              // 64 x 128 fp32 (32 KB)

    const int z = blockIdx.z;
    const __hip_bfloat16* A  = z ? A1 : A0;
    const __hip_bfloat16* Bt = z ? B1 : B0;
    const float* bias        = z ? bias1 : bias0;
    float* C                 = z ? C1 : C0;
    const int K              = z ? 128 : 64;

    const int tid  = threadIdx.x;
    const int lane = tid & 63;
    const int wave = tid >> 6;
    const int wr = wave >> 1, wc = wave & 1;
    const int row0 = blockIdx.y * 128;
    const int col0 = blockIdx.x * 128;

    f32x4 acc[4][4] = {};

    for (int kb = 0; kb < K; kb += 64) {
        #pragma unroll
        for (int i = 0; i < 4; ++i) {
            int id = tid + i * 256;
            int r = id >> 3;
            int c = id & 7;
            int cs = c ^ (r & 7);
            gload_lds16(&A[(size_t)(row0 + r) * K + kb + cs * 8], &Alds[id * 8]);
        }
        #pragma unroll
        for (int i = 0; i < 4; ++i) {
            int id = tid + i * 256;
            int r = id >> 3;
            int c = id & 7;
            int cs = c ^ (r & 7);
            int n = col0 + r;
            if (n >= N) n = N - 1;            // clamp: garbage cols never stored
            gload_lds16(&Bt[(size_t)n * K + kb + cs * 8], &Blds[id * 8]);
        }
        __syncthreads();

        const int frow = lane & 15;
        const int chi  = lane >> 4;
        #pragma unroll
        for (int kk = 0; kk < 2; ++kk) {
            short8 af[4], bf[4];
            #pragma unroll
            for (int m = 0; m < 4; ++m) {
                int r = wr * 64 + m * 16 + frow;
                int cs = (kk * 4 + chi) ^ (r & 7);
                af[m] = *(const short8*)&Alds[r * 64 + cs * 8];
            }
            #pragma unroll
            for (int n = 0; n < 4; ++n) {
                int r = wc * 64 + n * 16 + frow;
                int cs = (kk * 4 + chi) ^ (r & 7);
                bf[n] = *(const short8*)&Blds[r * 64 + cs * 8];
            }
            #pragma unroll
            for (int m = 0; m < 4; ++m)
                #pragma unroll
                for (int n = 0; n < 4; ++n)
                    acc[m][n] = __builtin_amdgcn_mfma_f32_16x16x32_bf16(
                        af[m], bf[n], acc[m][n], 0, 0, 0);
        }
        __syncthreads();
    }

    // ---- epilogue: 2 passes of 64 rows x 128 cols through LDS ----
    const int g = lane >> 4;
    const int fcol = lane & 15;
    const int ccr = tid & 127;
    const int bc  = col0 + ccr;
    const float bv = (bc < N) ? bias[bc] : 0.f;

    #pragma unroll
    for (int p = 0; p < 2; ++p) {
        if (p) __syncthreads();
        #pragma unroll
        for (int mm = 0; mm < 2; ++mm) {
            #pragma unroll
            for (int n = 0; n < 4; ++n) {
                int rl = wr * 32 + mm * 16 + g * 4;
                int cc = wc * 64 + n * 16 + fcol;
                int ccs = cc ^ (((rl >> 2) & 1) << 4);
                #pragma unroll
                for (int r = 0; r < 4; ++r)
                    scr[(rl + r) * 128 + ccs] = acc[2 * p + mm][n][r];
            }
        }
        __syncthreads();
        if (bc < N) {
            #pragma unroll
            for (int i = 0; i < 32; ++i) {
                int id = i * 256 + tid;
                int rl = id >> 7;
                int ccs = ccr ^ (((rl >> 2) & 1) << 4);
                int grow = row0 + p * 32 + ((rl >> 5) << 6) + (rl & 31);
                C[(size_t)grow * N + bc] = scr[rl * 128 + ccs] + bv;
            }
        }
    }
}

extern "C" void kernel_launch(void* const* d_in, const int* in_sizes, int n_in,
                              void* d_out, int out_size, void* d_ws, size_t ws_size,
                              hipStream_t stream)
{
    const float* x   = (const float*)d_in[0];
    const float* fs  = (const float*)d_in[1];
    const float* qw  = (const float*)d_in[2];
    const float* qw1 = (const float*)d_in[3];
    const float* qb1 = (const float*)d_in[4];
    const float* qw2 = (const float*)d_in[5];
    const float* qb2 = (const float*)d_in[6];
    const float* cw1 = (const float*)d_in[7];
    const float* cb1 = (const float*)d_in[8];
    const float* cw2 = (const float*)d_in[9];
    const float* cb2 = (const float*)d_in[10];
    const float* cw3 = (const float*)d_in[11];
    const float* cb3 = (const float*)d_in[12];

    float* q_logits = (float*)d_out;
    float* c_logits = q_logits + (size_t)BATCH * NCLS;
    float* qf_out   = c_logits + (size_t)BATCH * NCLS;

    const int NPAD = 3200;
    __hip_bfloat16* hq   = (__hip_bfloat16*)d_ws;              // 8192 x 64
    __hip_bfloat16* h2   = hq + (size_t)BATCH * 64;            // 8192 x 128
    __hip_bfloat16* qw2t = h2 + (size_t)BATCH * 128;           // 3200 x 64
    __hip_bfloat16* cw3t = qw2t + (size_t)NPAD * 64;           // 3200 x 128

    prep_kernel<<<NBQ + NBC + NBT, 256, 0, stream>>>(
        x, fs, qw, qw1, qb1, cw1, cb1, cw2, cb2, qw2, cw3,
        qf_out, hq, h2, qw2t, cw3t);

    dim3 grid((NCLS + 127) / 128, BATCH / 128, 2);
    gemm_mfma_dual<<<grid, 256, 0, stream>>>(hq, qw2t, qb2, q_logits,
                                             h2, cw3t, cb3, c_logits, NCLS);
}

// Round 8
// 96.393 us; speedup vs baseline: 1.4830x; 1.0718x over previous
//
#include <hip/hip_runtime.h>
#include <hip/hip_bf16.h>
#include <math.h>

#define NQ 7
#define NL 6
#define BATCH 8192
#define NPCA 32
#define NCLS 3129
#define NGATE 42

#define NBQ 2048            // quantum blocks (4 samples each)
#define NBC 512             // chead blocks (16 rows each)
#define NBX 49              // transpose x-tiles = ceil(3129/64)
#define NBT (3 * NBX)       // transpose blocks

// gemm grid geometry (1-D, XCD-swizzled)
#define GXB 25              // col tiles = ceil(3129/128)
#define GYB 64              // row tiles = 8192/128
#define GNB (GXB * GYB * 2) // 3200 blocks; 3200 % 8 == 0 -> simple swizzle bijective
#define GCPX (GNB / 8)      // 400 blocks per XCD

typedef __attribute__((ext_vector_type(8))) short short8;
typedef __attribute__((ext_vector_type(4))) float f32x4;

__device__ __forceinline__ void gload_lds16(const void* g, void* l) {
    __builtin_amdgcn_global_load_lds(
        (const __attribute__((address_space(1))) void*)g,
        (__attribute__((address_space(3))) void*)l, 16, 0, 0);
}

// ---------------------------------------------------------------------------
// Fused prep kernel: blockIdx.x selects role. Quantum math: per-gate HW trig
// for data-dependent gates (g<32); gates 32..41 are the zero-padded features
// (theta = w0 only, batch-invariant) -> their trig hoisted out of the serial
// chain into a pipelined pre-loop. CNOT ring: constant-mask shfl_xor (DPP).
// ---------------------------------------------------------------------------
__global__ __launch_bounds__(256) void prep_kernel(
    const float* __restrict__ x,        // B x 32
    const float* __restrict__ fscale,   // 32
    const float* __restrict__ qw,       // 6 x 7 x 2
    const float* __restrict__ qh_w1,    // 7 x 64
    const float* __restrict__ qh_b1,    // 64
    const float* __restrict__ cw1, const float* __restrict__ cb1,
    const float* __restrict__ cw2, const float* __restrict__ cb2,
    const float* __restrict__ qw2, const float* __restrict__ cw3,
    float* __restrict__ qf_out,             // B x 7 fp32 (d_out)
    __hip_bfloat16* __restrict__ hq_out,    // B x 64
    __hip_bfloat16* __restrict__ h2_out,    // B x 128
    __hip_bfloat16* __restrict__ qw2t,      // 3200 x 64
    __hip_bfloat16* __restrict__ cw3t)      // 3200 x 128
{
    __shared__ alignas(16) unsigned char smem[18752];
    const int bid = blockIdx.x;
    const int tid = threadIdx.x;

    if (bid < NBQ) {
        // ================= quantum role =================
        float* pzc = (float*)smem;
        float* pzs = pzc + NGATE;
        float* w0s = pzs + NGATE;
        if (tid < NGATE) {
            float t = qw[tid * 2 + 1] * 0.5f;
            float s, c;
            sincosf(t, &s, &c);
            pzs[tid] = s; pzc[tid] = c;
            w0s[tid] = qw[tid * 2 + 0];
        }
        __syncthreads();

        const int lane = tid & 63;
        const int wave = tid >> 6;
        const int sample = bid * 4 + wave;

        float myfeat = 0.f;
        if (lane < NPCA) myfeat = atanf(x[sample * NPCA + lane] * fscale[lane]);

        // batch-invariant gates (zero-padded features): trig outside the chain,
        // 10 independent sincos pipeline instead of serializing in the loop
        float rs[NGATE - NPCA], rc[NGATE - NPCA];
        #pragma unroll
        for (int g = NPCA; g < NGATE; ++g) {
            float th = w0s[g] * 0.5f;
            rs[g - NPCA] = __sinf(th);
            rc[g - NPCA] = __cosf(th);
        }

        float s0r = (lane == 0) ? 1.f : 0.f, s0i = 0.f, s1r = 0.f, s1i = 0.f;

        #pragma unroll
        for (int layer = 0; layer < NL; ++layer) {
            #pragma unroll
            for (int q = 0; q < NQ; ++q) {
                const int g = layer * NQ + q;
                const int b = NQ - 1 - q;
                float s, c;
                if (g < NPCA) {
                    float fv = __shfl(myfeat, g);
                    float th = (fv + w0s[g]) * 0.5f;
                    s = __sinf(th); c = __cosf(th);   // |th| < 1 rad: HW trig safe
                } else {
                    s = rs[g - NPCA]; c = rc[g - NPCA];
                }
                if (b == 0) {
                    float n0r = c * s0r - s * s1r, n0i = c * s0i - s * s1i;
                    float n1r = s * s0r + c * s1r, n1i = s * s0i + c * s1i;
                    s0r = n0r; s0i = n0i; s1r = n1r; s1i = n1i;
                } else {
                    int m = 1 << (b - 1);
                    float p0r = __shfl_xor(s0r, m), p0i = __shfl_xor(s0i, m);
                    float p1r = __shfl_xor(s1r, m), p1i = __shfl_xor(s1i, m);
                    if (((lane >> (b - 1)) & 1) == 0) {
                        s0r = c * s0r - s * p0r; s0i = c * s0i - s * p0i;
                        s1r = c * s1r - s * p1r; s1i = c * s1i - s * p1i;
                    } else {
                        s0r = s * p0r + c * s0r; s0i = s * p0i + c * s0i;
                        s1r = s * p1r + c * s1r; s1i = s * p1i + c * s1i;
                    }
                }
                float pc = pzc[g], ps = pzs[g];
                if (b == 0) {
                    float u0 = pc * s0r + ps * s0i; s0i = pc * s0i - ps * s0r; s0r = u0;
                    float u1 = pc * s1r - ps * s1i; s1i = pc * s1i + ps * s1r; s1r = u1;
                } else {
                    float e = (((lane >> (b - 1)) & 1) == 0) ? ps : -ps;
                    float u0 = pc * s0r + e * s0i; s0i = pc * s0i - e * s0r; s0r = u0;
                    float u1 = pc * s1r + e * s1i; s1i = pc * s1i - e * s1r; s1r = u1;
                }
            }
            // sequential CNOT ring: constant-mask shfl_xor -> DPP/swizzle
            #pragma unroll
            for (int cq = 0; cq < NQ; ++cq) {
                if (cq == NQ - 1) {
                    float r = __shfl_xor(s1r, 32), im = __shfl_xor(s1i, 32);
                    s1r = r; s1i = im;
                } else if (cq == NQ - 2) {
                    if (lane & 1) {
                        float tr = s0r; s0r = s1r; s1r = tr;
                        float ti = s0i; s0i = s1i; s1i = ti;
                    }
                } else {
                    const int bc = NQ - 1 - cq;
                    const int bt = bc - 1;
                    int m = 1 << (bt - 1);
                    float p0r = __shfl_xor(s0r, m), p0i = __shfl_xor(s0i, m);
                    float p1r = __shfl_xor(s1r, m), p1i = __shfl_xor(s1i, m);
                    if ((lane >> (bc - 1)) & 1) {
                        s0r = p0r; s0i = p0i; s1r = p1r; s1i = p1i;
                    }
                }
            }
        }

        float p0 = s0r * s0r + s0i * s0i;
        float p1 = s1r * s1r + s1i * s1i;
        float psum = p0 + p1;
        float qf[7];
        #pragma unroll
        for (int k = 0; k < 6; ++k)
            qf[k] = (((lane >> (5 - k)) & 1) ? -psum : psum);
        qf[6] = p0 - p1;
        #pragma unroll
        for (int off = 32; off >= 1; off >>= 1) {
            #pragma unroll
            for (int k = 0; k < 7; ++k) qf[k] += __shfl_xor(qf[k], off);
        }

        float acc = qh_b1[lane];
        #pragma unroll
        for (int k = 0; k < 7; ++k) acc += qf[k] * qh_w1[k * 64 + lane];
        hq_out[sample * 64 + lane] = __float2bfloat16(fmaxf(acc, 0.f));
        if (lane < 7) qf_out[sample * 7 + lane] = qf[lane];

    } else if (bid < NBQ + NBC) {
        // ================= chead role =================
        float (*xs)[33]   = (float(*)[33])smem;            // 2112 B
        float (*h1s)[260] = (float(*)[260])(smem + 2112);  // 16640 B
        const int row0 = (bid - NBQ) * 16;

        for (int i = tid; i < 16 * 32; i += 256) {
            int r = i >> 5, k = i & 31;
            xs[r][k] = x[(row0 + r) * 32 + k];
        }
        __syncthreads();

        {
            float w1c[32];
            #pragma unroll
            for (int k = 0; k < 32; ++k) w1c[k] = cw1[k * 256 + tid];
            float bb = cb1[tid];
            #pragma unroll
            for (int r = 0; r < 16; ++r) {
                float a = bb;
                #pragma unroll
                for (int k = 0; k < 32; ++k) a += xs[r][k] * w1c[k];
                h1s[r][tid] = fmaxf(a, 0.f);
            }
        }
        __syncthreads();

        {
            const int c0 = (tid & 31) * 4;
            const int r0 = (tid >> 5) * 2;
            float4 bv = *(const float4*)&cb2[c0];
            float a0[4] = {bv.x, bv.y, bv.z, bv.w};
            float a1[4] = {bv.x, bv.y, bv.z, bv.w};
            for (int k = 0; k < 256; k += 4) {
                float4 h0 = *(const float4*)&h1s[r0][k];
                float4 h1 = *(const float4*)&h1s[r0 + 1][k];
                #pragma unroll
                for (int j = 0; j < 4; ++j) {
                    float4 w = *(const float4*)&cw2[(size_t)(k + j) * 128 + c0];
                    float hv0 = (j == 0) ? h0.x : (j == 1) ? h0.y : (j == 2) ? h0.z : h0.w;
                    float hv1 = (j == 0) ? h1.x : (j == 1) ? h1.y : (j == 2) ? h1.z : h1.w;
                    a0[0] += hv0 * w.x; a0[1] += hv0 * w.y; a0[2] += hv0 * w.z; a0[3] += hv0 * w.w;
                    a1[0] += hv1 * w.x; a1[1] += hv1 * w.y; a1[2] += hv1 * w.z; a1[3] += hv1 * w.w;
                }
            }
            #pragma unroll
            for (int rr = 0; rr < 2; ++rr) {
                float* a = rr ? a1 : a0;
                __hip_bfloat162 q0, q1;
                q0.x = __float2bfloat16(fmaxf(a[0], 0.f));
                q0.y = __float2bfloat16(fmaxf(a[1], 0.f));
                q1.x = __float2bfloat16(fmaxf(a[2], 0.f));
                q1.y = __float2bfloat16(fmaxf(a[3], 0.f));
                size_t base = (size_t)(row0 + r0 + rr) * 128 + c0;
                *(__hip_bfloat162*)&h2_out[base]     = q0;
                *(__hip_bfloat162*)&h2_out[base + 2] = q1;
            }
        }

    } else {
        // ================= transpose role =================
        float (*tile)[65] = (float(*)[65])smem;            // 16640 B
        const int t = bid - (NBQ + NBC);
        const int y = t / NBX;
        const int n0 = (t % NBX) * 64;
        const float* W; __hip_bfloat16* Wt; int K, k0;
        if (y == 0) { W = qw2; Wt = qw2t; K = 64;  k0 = 0; }
        else        { W = cw3; Wt = cw3t; K = 128; k0 = (y - 1) * 64; }

        #pragma unroll
        for (int i = 0; i < 16; ++i) {
            int id = tid + i * 256;
            int kr = id >> 6, nc = id & 63;
            int n = n0 + nc;
            tile[kr][nc] = (n < NCLS) ? W[(size_t)(k0 + kr) * NCLS + n] : 0.f;
        }
        __syncthreads();
        #pragma unroll
        for (int i = 0; i < 16; ++i) {
            int id = tid + i * 256;
            int nr = id >> 6, kc = id & 63;
            int n = n0 + nr;
            if (n < NCLS) Wt[(size_t)n * K + k0 + kc] = __float2bfloat16(tile[kc][nr]);
        }
    }
}

// ---------------------------------------------------------------------------
// Dual MFMA GEMM, 1-D grid with bijective XCD swizzle (3200 % 8 == 0).
// Logical order x-fastest: each XCD owns contiguous 128-row x full-N panels,
// so column-neighbor blocks (which share the misaligned 64B edge sectors of
// C rows, stride 12516B = 36 mod 64) land in the SAME L2 and their partial
// dirty lines merge before eviction instead of HBM read-modify-write.
// ---------------------------------------------------------------------------
__global__ __launch_bounds__(256) void gemm_mfma_dual(
    const __hip_bfloat16* __restrict__ A0, const __hip_bfloat16* __restrict__ B0,
    const float* __restrict__ bias0, float* __restrict__ C0,
    const __hip_bfloat16* __restrict__ A1, const __hip_bfloat16* __restrict__ B1,
    const float* __restrict__ bias1, float* __restrict__ C1, int N)
{
    __shared__ alignas(16) unsigned char shraw[32768];
    __hip_bfloat16* Alds = (__hip_bfloat16*)shraw;           // 128 x 64 (16 KB)
    __hip_bfloat16* Blds = Alds + 128 * 64;                  // 128 x 64 (16 KB)
    float* scr = (float*)shraw;                              // 64 x 128 fp32 (32 KB)

    // XCD swizzle: physical bid -> logical work id; XCD k gets logical
    // [k*GCPX, (k+1)*GCPX) contiguous (dispatch round-robins bid%8 -> XCD)
    const int logical = (blockIdx.x & 7) * GCPX + (blockIdx.x >> 3);
    const int z   = logical >= (GXB * GYB);
    const int rem = logical - z * (GXB * GYB);
    const int by  = rem / GXB;
    const int bx  = rem - by * GXB;

    const __hip_bfloat16* A  = z ? A1 : A0;
    const __hip_bfloat16* Bt = z ? B1 : B0;
    const float* bias        = z ? bias1 : bias0;
    float* C                 = z ? C1 : C0;
    const int K              = z ? 128 : 64;

    const int tid  = threadIdx.x;
    const int lane = tid & 63;
    const int wave = tid >> 6;
    const int wr = wave >> 1, wc = wave & 1;
    const int row0 = by * 128;
    const int col0 = bx * 128;

    f32x4 acc[4][4] = {};

    for (int kb = 0; kb < K; kb += 64) {
        #pragma unroll
        for (int i = 0; i < 4; ++i) {
            int id = tid + i * 256;
            int r = id >> 3;
            int c = id & 7;
            int cs = c ^ (r & 7);
            gload_lds16(&A[(size_t)(row0 + r) * K + kb + cs * 8], &Alds[id * 8]);
        }
        #pragma unroll
        for (int i = 0; i < 4; ++i) {
            int id = tid + i * 256;
            int r = id >> 3;
            int c = id & 7;
            int cs = c ^ (r & 7);
            int n = col0 + r;
            if (n >= N) n = N - 1;            // clamp: garbage cols never stored
            gload_lds16(&Bt[(size_t)n * K + kb + cs * 8], &Blds[id * 8]);
        }
        __syncthreads();

        const int frow = lane & 15;
        const int chi  = lane >> 4;
        #pragma unroll
        for (int kk = 0; kk < 2; ++kk) {
            short8 af[4], bf[4];
            #pragma unroll
            for (int m = 0; m < 4; ++m) {
                int r = wr * 64 + m * 16 + frow;
                int cs = (kk * 4 + chi) ^ (r & 7);
                af[m] = *(const short8*)&Alds[r * 64 + cs * 8];
            }
            #pragma unroll
            for (int n = 0; n < 4; ++n) {
                int r = wc * 64 + n * 16 + frow;
                int cs = (kk * 4 + chi) ^ (r & 7);
                bf[n] = *(const short8*)&Blds[r * 64 + cs * 8];
            }
            #pragma unroll
            for (int m = 0; m < 4; ++m)
                #pragma unroll
                for (int n = 0; n < 4; ++n)
                    acc[m][n] = __builtin_amdgcn_mfma_f32_16x16x32_bf16(
                        af[m], bf[n], acc[m][n], 0, 0, 0);
        }
        __syncthreads();
    }

    // ---- epilogue: 2 passes of 64 rows x 128 cols through LDS ----
    const int g = lane >> 4;
    const int fcol = lane & 15;
    const int ccr = tid & 127;
    const int bc  = col0 + ccr;
    const float bv = (bc < N) ? bias[bc] : 0.f;

    #pragma unroll
    for (int p = 0; p < 2; ++p) {
        if (p) __syncthreads();
        #pragma unroll
        for (int mm = 0; mm < 2; ++mm) {
            #pragma unroll
            for (int n = 0; n < 4; ++n) {
                int rl = wr * 32 + mm * 16 + g * 4;
                int cc = wc * 64 + n * 16 + fcol;
                int ccs = cc ^ (((rl >> 2) & 1) << 4);
                #pragma unroll
                for (int r = 0; r < 4; ++r)
                    scr[(rl + r) * 128 + ccs] = acc[2 * p + mm][n][r];
            }
        }
        __syncthreads();
        if (bc < N) {
            #pragma unroll
            for (int i = 0; i < 32; ++i) {
                int id = i * 256 + tid;
                int rl = id >> 7;
                int ccs = ccr ^ (((rl >> 2) & 1) << 4);
                int grow = row0 + p * 32 + ((rl >> 5) << 6) + (rl & 31);
                C[(size_t)grow * N + bc] = scr[rl * 128 + ccs] + bv;
            }
        }
    }
}

extern "C" void kernel_launch(void* const* d_in, const int* in_sizes, int n_in,
                              void* d_out, int out_size, void* d_ws, size_t ws_size,
                              hipStream_t stream)
{
    const float* x   = (const float*)d_in[0];
    const float* fs  = (const float*)d_in[1];
    const float* qw  = (const float*)d_in[2];
    const float* qw1 = (const float*)d_in[3];
    const float* qb1 = (const float*)d_in[4];
    const float* qw2 = (const float*)d_in[5];
    const float* qb2 = (const float*)d_in[6];
    const float* cw1 = (const float*)d_in[7];
    const float* cb1 = (const float*)d_in[8];
    const float* cw2 = (const float*)d_in[9];
    const float* cb2 = (const float*)d_in[10];
    const float* cw3 = (const float*)d_in[11];
    const float* cb3 = (const float*)d_in[12];

    float* q_logits = (float*)d_out;
    float* c_logits = q_logits + (size_t)BATCH * NCLS;
    float* qf_out   = c_logits + (size_t)BATCH * NCLS;

    const int NPAD = 3200;
    __hip_bfloat16* hq   = (__hip_bfloat16*)d_ws;              // 8192 x 64
    __hip_bfloat16* h2   = hq + (size_t)BATCH * 64;            // 8192 x 128
    __hip_bfloat16* qw2t = h2 + (size_t)BATCH * 128;           // 3200 x 64
    __hip_bfloat16* cw3t = qw2t + (size_t)NPAD * 64;           // 3200 x 128

    prep_kernel<<<NBQ + NBC + NBT, 256, 0, stream>>>(
        x, fs, qw, qw1, qb1, cw1, cb1, cw2, cb2, qw2, cw3,
        qf_out, hq, h2, qw2t, cw3t);

    gemm_mfma_dual<<<GNB, 256, 0, stream>>>(hq, qw2t, qb2, q_logits,
                                            h2, cw3t, cb3, c_logits, NCLS);
}